// Round 11
// baseline (119.678 us; speedup 1.0000x reference)
//
#include <hip/hip_runtime.h>

// Fake-quant (UniformAffineQuantizer): per-128-element-group asymmetric 4-bit
// fake quantization of an 8192x8192 f32 tensor. Bit-exact since R8.
//
// NUMERICS (locked — do not change; R8 absmax 0.0): harness ref is the
// XLA-simplified chain:
//   s  = clip((max-min) * RN(1/15), 1e-5, 1e4)   [mul by folded reciprocal]
//   zp = clip(-min / s, -1e4, 1e4); rzp = RNE(zp)  [true IEEE divide]
//   q  = RNE(x * RN(1/s))                        [mul by reciprocal(1/s)]
//   out= (clamp(q+rzp,0,15) - rzp) * s
//
// PERF LOG:
//  R8  grid-stride, 4 elems/lane, 1 load burst:   113.3 us (4.74 TB/s)
//  R9  8 elems/lane + nontemporal:                117.6 us (NT store hurts)
//  R10 one-shot, 16 elems/lane, 4-load burst:     113.9 us
//  => burst-width MLP is NOT the limiter. Theory: in-flight DUTY CYCLE is —
//  every variant has zero reads outstanding during its ~700-cy compute tail
//  (vmcnt(0) precedes the butterfly), so outstanding-bytes/CU ~ 16 KiB vs
//  the ~20 KiB BW*loaded-latency product -> caps at ~75% of copy BW.
//  R11: R8 shape + depth-1 cross-iteration PREFETCH (T14): load tile k+1
//  before processing tile k -> a read stays in flight through the whole
//  compute phase. Uniform trip count (32 iters, wave-uniform 'more').

using f32x4 = __attribute__((ext_vector_type(4))) float;

__global__ __launch_bounds__(256) void fakequant_pf(
    const f32x4* __restrict__ x, f32x4* __restrict__ out, int nvec)
{
    const float C15 = 1.0f / 15.0f;   // RN(1/15), constant-folded
    const int stride = gridDim.x * blockDim.x;

    int v = blockIdx.x * blockDim.x + threadIdx.x;
    if (v >= nvec) return;

    f32x4 d = x[v];                   // prologue load
    for (;;) {
        const int vn = v + stride;
        const bool more = vn < nvec;  // wave-uniform (stride % 64 == 0)
        f32x4 dn;
        if (more) dn = x[vn];         // PREFETCH: in flight during compute

        // ---- process current tile (R8's proven chain) ----
        float mn = fminf(fminf(d[0], d[1]), fminf(d[2], d[3]));
        float mx = fmaxf(fmaxf(d[0], d[1]), fmaxf(d[2], d[3]));

        // group = 32 consecutive lanes (32 x 4 elems = 128)
        #pragma unroll
        for (int off = 16; off > 0; off >>= 1) {
            mn = fminf(mn, __shfl_xor(mn, off, 32));
            mx = fmaxf(mx, __shfl_xor(mx, off, 32));
        }

        float s = (mx - mn) * C15;
        s = fminf(fmaxf(s, 1e-5f), 1e4f);
        float zp = (-mn) / s;                  // true IEEE divide
        zp = fminf(fmaxf(zp, -1e4f), 1e4f);
        float rzp = rintf(zp);
        float rs = 1.0f / s;                   // true IEEE divide, once

        f32x4 o;
        #pragma unroll
        for (int i = 0; i < 4; ++i)
            o[i] = (fminf(fmaxf(rintf(d[i] * rs) + rzp, 0.0f), 15.0f) - rzp) * s;

        out[v] = o;

        if (!more) break;
        d = dn;
        v = vn;
    }
}

extern "C" void kernel_launch(void* const* d_in, const int* in_sizes, int n_in,
                              void* d_out, int out_size, void* d_ws, size_t ws_size,
                              hipStream_t stream)
{
    const float* x = (const float*)d_in[0];
    float* o = (float*)d_out;

    const int n = in_sizes[0];          // 8192*8192 = 67108864
    const int nvec = n / 4;             // 16777216 float4 elements

    // 2048 blocks x 256 thr: 32 iters/thread, stride preserves the
    // 32-lane <-> 128-elem group alignment; trip count uniform.
    const int block = 256;
    const int grid = 2048;

    fakequant_pf<<<grid, block, 0, stream>>>(
        (const f32x4*)x, (f32x4*)o, nvec);
}

// Round 13
// 87.419 us; speedup vs baseline: 1.3690x; 1.3690x over previous
//
#include <hip/hip_runtime.h>

// Fake-quant (UniformAffineQuantizer): per-128-element-group asymmetric 4-bit
// fake quantization of an 8192x8192 f32 tensor. Bit-exact since R8.
//
// NUMERICS (locked — do not change; R8 absmax 0.0): harness ref is the
// XLA-simplified chain:
//   s  = clip((max-min) * RN(1/15), 1e-5, 1e4)   [mul by folded reciprocal]
//   zp = clip(-min / s, -1e4, 1e4); rzp = RNE(zp)  [true IEEE divide]
//   q  = RNE(x * RN(1/s))                        [mul by reciprocal(1/s)]
//   out= (clamp(q+rzp,0,15) - rzp) * s
//
// PERF LOG:
//  R8  grid-stride, 4 elems/lane, 1 burst:      113.3 us (4.74 TB/s)
//  R9  8 elems/lane + NT load+store:            117.6 us
//  R10 one-shot, 16 elems/lane, 4-load burst:   113.9 us
//  R11 depth-1 cross-iter prefetch:             119.7 us
//  R12 ds_swizzle probe: COMPILE FAIL (pattern must be constant int) —
//      fixed here via template<int PAT>. Theory unchanged: __shfl_xor(.,off,32)
//      lowers to v_xor+v_lshl+ds_bpermute (3 insts/step x10 on the serial
//      reduce chain); BitMode ds_swizzle does each xor step in 1 inst
//      (0x041F/0x081F/0x101F/0x201F/0x401F = xor within 32-lane groups).
//      Plus NT on LOADS only (R9's regression was the NT STORE bypassing L2).

using f32x4 = __attribute__((ext_vector_type(4))) float;

template <int PAT>
__device__ __forceinline__ float swz_min(float v) {
    int i = __builtin_amdgcn_ds_swizzle(__float_as_int(v), PAT);
    return fminf(v, __int_as_float(i));
}
template <int PAT>
__device__ __forceinline__ float swz_max(float v) {
    int i = __builtin_amdgcn_ds_swizzle(__float_as_int(v), PAT);
    return fmaxf(v, __int_as_float(i));
}

__global__ __launch_bounds__(256) void fakequant_swz(
    const f32x4* __restrict__ x, f32x4* __restrict__ out, int nvec)
{
    const float C15 = 1.0f / 15.0f;   // RN(1/15), constant-folded
    const int stride = gridDim.x * blockDim.x;

    for (int v = blockIdx.x * blockDim.x + threadIdx.x; v < nvec; v += stride) {
        f32x4 d = __builtin_nontemporal_load(&x[v]);   // NT read (evict-first)

        float mn = fminf(fminf(d[0], d[1]), fminf(d[2], d[3]));
        float mx = fmaxf(fmaxf(d[0], d[1]), fmaxf(d[2], d[3]));

        // butterfly over 32-lane group, BitMode ds_swizzle (1 inst/step):
        // offset = (xor_mask<<10) | (0<<5) | 0x1F
        mn = swz_min<0x041F>(mn); mx = swz_max<0x041F>(mx);   // xor 1
        mn = swz_min<0x081F>(mn); mx = swz_max<0x081F>(mx);   // xor 2
        mn = swz_min<0x101F>(mn); mx = swz_max<0x101F>(mx);   // xor 4
        mn = swz_min<0x201F>(mn); mx = swz_max<0x201F>(mx);   // xor 8
        mn = swz_min<0x401F>(mn); mx = swz_max<0x401F>(mx);   // xor 16

        // ---- locked numerics chain ----
        float s = (mx - mn) * C15;
        s = fminf(fmaxf(s, 1e-5f), 1e4f);
        float zp = (-mn) / s;                  // true IEEE divide
        zp = fminf(fmaxf(zp, -1e4f), 1e4f);
        float rzp = rintf(zp);
        float rs = 1.0f / s;                   // true IEEE divide, once

        f32x4 o;
        #pragma unroll
        for (int i = 0; i < 4; ++i)
            o[i] = (fminf(fmaxf(rintf(d[i] * rs) + rzp, 0.0f), 15.0f) - rzp) * s;

        out[v] = o;
    }
}

extern "C" void kernel_launch(void* const* d_in, const int* in_sizes, int n_in,
                              void* d_out, int out_size, void* d_ws, size_t ws_size,
                              hipStream_t stream)
{
    const float* x = (const float*)d_in[0];
    float* o = (float*)d_out;

    const int n = in_sizes[0];          // 8192*8192 = 67108864
    const int nvec = n / 4;             // 16777216 float4 elements

    // 2048 blocks x 256 thr: 32 iters/thread; the grid stride is a multiple
    // of 32 lanes -> 32-lane <-> 128-elem group alignment preserved.
    const int block = 256;
    const int grid = 2048;

    fakequant_swz<<<grid, block, 0, stream>>>(
        (const f32x4*)x, (f32x4*)o, nvec);
}